// Round 1
// baseline (16371.579 us; speedup 1.0000x reference)
//
#include <hip/hip_runtime.h>
#include <math.h>

#define BTOK 8      // tokens per block
#define TPT 32      // threads per token
#define ROW 520     // padded LDS row (514 used)
#define NTOK 131072 // B*S = 2048*64
#define EPS 1e-5f

__device__ __forceinline__ float rsum32(float v) {
    v += __shfl_xor(v, 1);
    v += __shfl_xor(v, 2);
    v += __shfl_xor(v, 4);
    v += __shfl_xor(v, 8);
    v += __shfl_xor(v, 16);
    return v;
}

__device__ __forceinline__ void load16(const float* __restrict__ p, float v[16]) {
    const float4* q = (const float4*)p;
    float4 a = q[0], b = q[1], c = q[2], d = q[3];
    v[0]=a.x; v[1]=a.y; v[2]=a.z; v[3]=a.w;
    v[4]=b.x; v[5]=b.y; v[6]=b.z; v[7]=b.w;
    v[8]=c.x; v[9]=c.y; v[10]=c.z; v[11]=c.w;
    v[12]=d.x; v[13]=d.y; v[14]=d.z; v[15]=d.w;
}

// LN + softplus on primal, JVP through LN+softplus on two tangents; store back to LDS.
__device__ __forceinline__ void ln_jvp_store(
    float pre[16], float up0[16], float up1[16],
    const float* __restrict__ gg, const float* __restrict__ bbe, int n0,
    float* __restrict__ xrow, float* __restrict__ u0row, float* __restrict__ u1row)
{
    float s1 = 0.f, s2 = 0.f, a0 = 0.f, x0 = 0.f, a1 = 0.f, x1 = 0.f;
#pragma unroll
    for (int j = 0; j < 16; j++) {
        s1 += pre[j];
        s2 += pre[j] * pre[j];
        a0 += up0[j];
        x0 += pre[j] * up0[j];
        a1 += up1[j];
        x1 += pre[j] * up1[j];
    }
    s1 = rsum32(s1); s2 = rsum32(s2);
    a0 = rsum32(a0); x0 = rsum32(x0);
    a1 = rsum32(a1); x1 = rsum32(x1);

    const float inv = 1.0f / 512.0f;
    float mu  = s1 * inv;
    float var = s2 * inv - mu * mu;
    float rs  = rsqrtf(var + EPS);
    float dm0 = a0 * inv, dm1 = a1 * inv;
    float c0 = rs * (x0 * inv - mu * dm0);   // mean(xhat * u0)
    float c1 = rs * (x1 * inv - mu * dm1);   // mean(xhat * u1)

    float gv[16], bv[16];
    load16(gg + n0, gv);
    load16(bbe + n0, bv);
#pragma unroll
    for (int j = 0; j < 16; j++) {
        float xh = (pre[j] - mu) * rs;
        float y  = fmaf(xh, gv[j], bv[j]);
        float e  = expf(-fabsf(y));
        float sp = fmaxf(y, 0.f) + log1pf(e);          // stable softplus
        float sig = 1.0f / (1.0f + expf(-y));          // softplus'
        float grs = gv[j] * rs;
        float dy0 = grs * (up0[j] - dm0 - xh * c0);
        float dy1 = grs * (up1[j] - dm1 - xh * c1);
        xrow[2 + n0 + j]  = sp;
        u0row[2 + n0 + j] = sig * dy0;
        u1row[2 + n0 + j] = sig * dy1;
    }
}

__global__ __launch_bounds__(256) void ode_fused(
    const float* __restrict__ t, const float* __restrict__ z, const float* __restrict__ cond,
    const float* __restrict__ W0, const float* __restrict__ b0,
    const float* __restrict__ g0, const float* __restrict__ be0,
    const float* __restrict__ W1, const float* __restrict__ b1,
    const float* __restrict__ g1, const float* __restrict__ be1,
    const float* __restrict__ W2, const float* __restrict__ b2,
    const float* __restrict__ g2, const float* __restrict__ be2,
    const float* __restrict__ W3, const float* __restrict__ b3,
    float* __restrict__ out)
{
    __shared__ float act[BTOK][ROW];
    __shared__ float tu0[BTOK][ROW];
    __shared__ float tu1[BTOK][ROW];

    const int tid = threadIdx.x;
    const int m   = tid / TPT;       // local token (0..7)
    const int idx = tid % TPT;       // lane within token group (0..31)
    const int gm  = blockIdx.x * BTOK + m;  // global token
    const int bi  = gm >> 6;         // batch index
    const int si  = gm & 63;         // seq index
    const int n0  = idx * 16;        // this thread's 16 output features

    const float te  = t[0];
    const float pos = (float)(si + 1) * (1.0f / 64.0f);

    float* xrow  = &act[m][0];
    float* u0row = &tu0[m][0];
    float* u1row = &tu1[m][0];

    // init: x = [te, pos, z0, z1, cond(128)]; tangent rows: leading 2 zeros
    if (idx == 0) {
        xrow[0] = te;  xrow[1] = pos;
        xrow[2] = z[gm * 2 + 0];
        xrow[3] = z[gm * 2 + 1];
        u0row[0] = 0.f; u0row[1] = 0.f;
        u1row[0] = 0.f; u1row[1] = 0.f;
    }
    for (int i = idx; i < 128; i += TPT)
        xrow[4 + i] = cond[bi * 128 + i];
    // token group lives within one wave -> no barrier needed anywhere

    float pre[16], up0[16], up1[16];

    // ---------------- layer 0: Kin=132, primal GEMM; tangent = W0 rows 2,3 ----
    load16(b0 + n0, pre);
    for (int k = 0; k < 132; k++) {
        float xk = xrow[k];
        float w[16];
        load16(W0 + k * 512 + n0, w);
#pragma unroll
        for (int j = 0; j < 16; j++)
            pre[j] = fmaf(xk, w[j], pre[j]);
    }
    load16(W0 + 2 * 512 + n0, up0);   // tangent e0: picks row te+0 -> x index 2
    load16(W0 + 3 * 512 + n0, up1);   // tangent e1: x index 3
    ln_jvp_store(pre, up0, up1, g0, be0, n0, xrow, u0row, u1row);

    // ---------------- layers 1,2: Kin=514, primal + 2 tangent GEMMs ----------
    const float* Ws[2]  = {W1, W2};
    const float* bs[2]  = {b1, b2};
    const float* gs[2]  = {g1, g2};
    const float* bes[2] = {be1, be2};
    for (int L = 0; L < 2; L++) {
        const float* W = Ws[L];
        load16(bs[L] + n0, pre);
#pragma unroll
        for (int j = 0; j < 16; j++) { up0[j] = 0.f; up1[j] = 0.f; }
        for (int k = 0; k < 514; k++) {
            float xk  = xrow[k];
            float a0k = u0row[k];
            float a1k = u1row[k];
            float w[16];
            load16(W + k * 512 + n0, w);
#pragma unroll
            for (int j = 0; j < 16; j++) {
                pre[j] = fmaf(xk,  w[j], pre[j]);
                up0[j] = fmaf(a0k, w[j], up0[j]);
                up1[j] = fmaf(a1k, w[j], up1[j]);
            }
        }
        ln_jvp_store(pre, up0, up1, gs[L], bes[L], n0, xrow, u0row, u1row);
    }

    // ---------------- layer 3: Kin=514, Nout=2; z_dot + divergence -----------
    float a0 = 0.f, a1 = 0.f, d0 = 0.f, d1 = 0.f;
    for (int k = idx; k < 514; k += TPT) {
        float w0 = W3[k * 2 + 0];
        float w1 = W3[k * 2 + 1];
        float xk = xrow[k];
        a0 = fmaf(xk, w0, a0);
        a1 = fmaf(xk, w1, a1);
        d0 = fmaf(u0row[k], w0, d0);
        d1 = fmaf(u1row[k], w1, d1);
    }
    a0 = rsum32(a0); a1 = rsum32(a1);
    d0 = rsum32(d0); d1 = rsum32(d1);
    if (idx == 0) {
        out[gm * 2 + 0] = a0 + b3[0];
        out[gm * 2 + 1] = a1 + b3[1];
        out[NTOK * 2 + gm] = -(d0 + d1);   // reference returns -divergence
    }
}

extern "C" void kernel_launch(void* const* d_in, const int* in_sizes, int n_in,
                              void* d_out, int out_size, void* d_ws, size_t ws_size,
                              hipStream_t stream) {
    const float* t    = (const float*)d_in[0];
    const float* z    = (const float*)d_in[1];
    const float* cond = (const float*)d_in[2];
    const float* W0   = (const float*)d_in[3];
    const float* b0   = (const float*)d_in[4];
    const float* g0   = (const float*)d_in[5];
    const float* be0  = (const float*)d_in[6];
    const float* W1   = (const float*)d_in[7];
    const float* b1   = (const float*)d_in[8];
    const float* g1   = (const float*)d_in[9];
    const float* be1  = (const float*)d_in[10];
    const float* W2   = (const float*)d_in[11];
    const float* b2   = (const float*)d_in[12];
    const float* g2   = (const float*)d_in[13];
    const float* be2  = (const float*)d_in[14];
    const float* W3   = (const float*)d_in[15];
    const float* b3   = (const float*)d_in[16];
    float* out = (float*)d_out;

    dim3 grid(NTOK / BTOK);   // 16384 blocks
    dim3 block(BTOK * TPT);   // 256 threads
    hipLaunchKernelGGL(ode_fused, grid, block, 0, stream,
                       t, z, cond, W0, b0, g0, be0, W1, b1, g1, be1,
                       W2, b2, g2, be2, W3, b3, out);
}

// Round 2
// 1445.138 us; speedup vs baseline: 11.3287x; 11.3287x over previous
//
#include <hip/hip_runtime.h>
#include <math.h>

typedef unsigned short ushort_t;
typedef unsigned int uint_t;
typedef __attribute__((ext_vector_type(8))) short bf16x8;
typedef __attribute__((ext_vector_type(4))) float f32x4;

#define NTOK 131072          // B*S
#define TM 16                // tokens per block
#define SROW 584             // A row stride in bf16 elems (292 dw, 292%32==4 -> conflict-free)
#define K0P 160              // layer0 K padded (132 -> 160)
#define KHP 544              // hidden layers K padded (514 -> 544)
#define EPS 1e-5f

__device__ __forceinline__ ushort_t f2bf(float f) {
    uint_t x = __float_as_uint(f);
    x += 0x7FFFu + ((x >> 16) & 1u);   // RNE
    return (ushort_t)(x >> 16);
}
__device__ __forceinline__ float bf2f(ushort_t u) {
    return __uint_as_float(((uint_t)u) << 16);
}

// ---- weight prep: W[K][512] fp32 -> Wt[n][k] bf16, zero-padded to Kpad ----
__global__ __launch_bounds__(256) void prep_w(const float* __restrict__ W,
                                              ushort_t* __restrict__ dst,
                                              int K, int Kpad) {
    int n = blockIdx.x;            // 0..511
    for (int k = threadIdx.x; k < Kpad; k += 256) {
        float v = (k < K) ? W[k * 512 + n] : 0.0f;
        dst[n * Kpad + k] = f2bf(v);
    }
}

__global__ __launch_bounds__(256, 2) void ode_mfma(
    const float* __restrict__ t, const float* __restrict__ z, const float* __restrict__ cond,
    const ushort_t* __restrict__ Wt0, const ushort_t* __restrict__ Wt1, const ushort_t* __restrict__ Wt2,
    const float* __restrict__ b0, const float* __restrict__ g0, const float* __restrict__ be0,
    const float* __restrict__ b1, const float* __restrict__ g1, const float* __restrict__ be1,
    const float* __restrict__ b2, const float* __restrict__ g2, const float* __restrict__ be2,
    const float* __restrict__ W3, const float* __restrict__ b3,
    float* __restrict__ out)
{
    __shared__ ushort_t A_s[48 * SROW];       // rows 0..15 primal x, 16..31 u0, 32..47 u1
    __shared__ float stats[4][TM][6];

    const int tid  = threadIdx.x;
    const int w    = tid >> 6;      // wave 0..3
    const int lane = tid & 63;
    const int q    = lane >> 4;     // quad 0..3
    const int c16  = lane & 15;
    const int nb   = w * 128;       // wave's column base

    // ---------------- init A ----------------
    {   // zero all of A (as dwords)
        uint_t* A32 = (uint_t*)A_s;
        for (int i = tid; i < 48 * SROW / 2; i += 256) A32[i] = 0u;
    }
    __syncthreads();
    const float te = t[0];
    if (tid < TM) {
        int tok = tid;
        int gm  = blockIdx.x * TM + tok;
        int si  = gm & 63;
        float pos = (float)(si + 1) * (1.0f / 64.0f);
        A_s[tok * SROW + 0] = f2bf(te);
        A_s[tok * SROW + 1] = f2bf(pos);
        A_s[tok * SROW + 2] = f2bf(z[gm * 2 + 0]);
        A_s[tok * SROW + 3] = f2bf(z[gm * 2 + 1]);
        A_s[(16 + tok) * SROW + 2] = 0x3F80;   // u0 = e0 (bf16 1.0)
        A_s[(32 + tok) * SROW + 3] = 0x3F80;   // u1 = e1
    }
    for (int i = tid; i < TM * 128; i += 256) {
        int tok = i >> 7, c = i & 127;
        int gm  = blockIdx.x * TM + tok;
        A_s[tok * SROW + 4 + c] = f2bf(cond[(gm >> 6) * 128 + c]);
    }
    __syncthreads();

    const ushort_t* Wts[3] = {Wt0, Wt1, Wt2};
    const float* bs[3]  = {b0, b1, b2};
    const float* gs[3]  = {g0, g1, g2};
    const float* bes[3] = {be0, be1, be2};
    const int kpads[3]  = {K0P, KHP, KHP};

    for (int L = 0; L < 3; L++) {
        const int Kpad = kpads[L];
        const int ksteps = Kpad / 32;
        const ushort_t* Wt = Wts[L];

        f32x4 acc[3][8];
#pragma unroll
        for (int m = 0; m < 3; m++)
#pragma unroll
            for (int j = 0; j < 8; j++) acc[m][j] = (f32x4){0.f, 0.f, 0.f, 0.f};

        // fragment prefetch pipeline
        bf16x8 afc[3], bfc[8], afn[3], bfn[8];
        const int koff = q * 8;
#pragma unroll
        for (int m = 0; m < 3; m++)
            afc[m] = *(const bf16x8*)&A_s[(m * 16 + c16) * SROW + koff];
#pragma unroll
        for (int j = 0; j < 8; j++)
            bfc[j] = *(const bf16x8*)&Wt[(nb + 16 * j + c16) * Kpad + koff];

        for (int ks = 0; ks < ksteps; ks++) {
            int kn = (ks + 1 < ksteps) ? (ks + 1) * 32 : ks * 32;  // clamp (dup load, unused)
#pragma unroll
            for (int m = 0; m < 3; m++)
                afn[m] = *(const bf16x8*)&A_s[(m * 16 + c16) * SROW + kn + koff];
#pragma unroll
            for (int j = 0; j < 8; j++)
                bfn[j] = *(const bf16x8*)&Wt[(nb + 16 * j + c16) * Kpad + kn + koff];
#pragma unroll
            for (int m = 0; m < 3; m++)
#pragma unroll
                for (int j = 0; j < 8; j++)
                    acc[m][j] = __builtin_amdgcn_mfma_f32_16x16x32_bf16(afc[m], bfc[j], acc[m][j], 0, 0, 0);
#pragma unroll
            for (int m = 0; m < 3; m++) afc[m] = afn[m];
#pragma unroll
            for (int j = 0; j < 8; j++) bfc[j] = bfn[j];
        }

        // bias (primal rows only)
        const float* bb = bs[L];
#pragma unroll
        for (int j = 0; j < 8; j++) {
            float bv = bb[nb + 16 * j + c16];
#pragma unroll
            for (int r = 0; r < 4; r++) acc[0][j][r] += bv;
        }

        // ---- LN stats: 6 sums per token over this wave's 128 cols ----
        float st[4][6];
#pragma unroll
        for (int r = 0; r < 4; r++) {
            float s1 = 0.f, s2 = 0.f, a0 = 0.f, x0 = 0.f, a1 = 0.f, x1 = 0.f;
#pragma unroll
            for (int j = 0; j < 8; j++) {
                float p = acc[0][j][r], u0 = acc[1][j][r], u1 = acc[2][j][r];
                s1 += p; s2 += p * p;
                a0 += u0; x0 += p * u0;
                a1 += u1; x1 += p * u1;
            }
            st[r][0] = s1; st[r][1] = s2; st[r][2] = a0; st[r][3] = x0; st[r][4] = a1; st[r][5] = x1;
        }
#pragma unroll
        for (int d = 1; d <= 8; d <<= 1)
#pragma unroll
            for (int r = 0; r < 4; r++)
#pragma unroll
                for (int s = 0; s < 6; s++) st[r][s] += __shfl_xor(st[r][s], d);
        if (c16 == 0) {
#pragma unroll
            for (int r = 0; r < 4; r++)
#pragma unroll
                for (int s = 0; s < 6; s++) stats[w][4 * q + r][s] = st[r][s];
        }
        __syncthreads();

        float mu[4], rs[4], dm0[4], c0[4], dm1[4], c1[4];
#pragma unroll
        for (int r = 0; r < 4; r++) {
            int tok = 4 * q + r;
            float s1 = 0.f, s2 = 0.f, a0 = 0.f, x0 = 0.f, a1 = 0.f, x1 = 0.f;
#pragma unroll
            for (int ww = 0; ww < 4; ww++) {
                s1 += stats[ww][tok][0]; s2 += stats[ww][tok][1];
                a0 += stats[ww][tok][2]; x0 += stats[ww][tok][3];
                a1 += stats[ww][tok][4]; x1 += stats[ww][tok][5];
            }
            const float inv = 1.0f / 512.0f;
            float m_  = s1 * inv;
            float var = s2 * inv - m_ * m_;
            float r_  = rsqrtf(var + EPS);
            mu[r] = m_; rs[r] = r_;
            dm0[r] = a0 * inv; c0[r] = r_ * (x0 * inv - m_ * dm0[r]);
            dm1[r] = a1 * inv; c1[r] = r_ * (x1 * inv - m_ * dm1[r]);
        }

        // ---- epilogue: softplus(LN) + JVP, write bf16 back to A ----
        const float* gg = gs[L];
        const float* bbev = bes[L];
#pragma unroll
        for (int j = 0; j < 8; j++) {
            int n = nb + 16 * j + c16;
            float gv = gg[n], bev = bbev[n];
#pragma unroll
            for (int r = 0; r < 4; r++) {
                int tok = 4 * q + r;
                float p  = acc[0][j][r], u0 = acc[1][j][r], u1 = acc[2][j][r];
                float xh = (p - mu[r]) * rs[r];
                float y  = fmaf(xh, gv, bev);
                float e  = __expf(-fabsf(y));
                float sp = fmaxf(y, 0.f) + log1pf(e);
                float sig = 1.0f / (1.0f + __expf(-y));
                float grs = gv * rs[r];
                float dy0 = grs * (u0 - dm0[r] - xh * c0[r]);
                float dy1 = grs * (u1 - dm1[r] - xh * c1[r]);
                A_s[tok * SROW + 2 + n]        = f2bf(sp);
                A_s[(16 + tok) * SROW + 2 + n] = f2bf(sig * dy0);
                A_s[(32 + tok) * SROW + 2 + n] = f2bf(sig * dy1);
            }
        }
        __syncthreads();
    }

    // ---------------- layer 3: Kin=514 -> 2 outputs + divergence ----------------
    {
        int tok = tid >> 4;       // 0..15
        int l16 = tid & 15;
        int gm  = blockIdx.x * TM + tok;
        float a0 = 0.f, a1 = 0.f, d0 = 0.f, d1 = 0.f;
        for (int k = l16; k < 514; k += 16) {
            float w0 = W3[k * 2 + 0];
            float w1 = W3[k * 2 + 1];
            float ax  = bf2f(A_s[tok * SROW + k]);
            float au0 = bf2f(A_s[(16 + tok) * SROW + k]);
            float au1 = bf2f(A_s[(32 + tok) * SROW + k]);
            a0 = fmaf(ax, w0, a0);
            a1 = fmaf(ax, w1, a1);
            d0 = fmaf(au0, w0, d0);
            d1 = fmaf(au1, w1, d1);
        }
#pragma unroll
        for (int d = 1; d <= 8; d <<= 1) {
            a0 += __shfl_xor(a0, d); a1 += __shfl_xor(a1, d);
            d0 += __shfl_xor(d0, d); d1 += __shfl_xor(d1, d);
        }
        if (l16 == 0) {
            out[gm * 2 + 0]    = a0 + b3[0];
            out[gm * 2 + 1]    = a1 + b3[1];
            out[NTOK * 2 + gm] = -(d0 + d1);
        }
    }
}

extern "C" void kernel_launch(void* const* d_in, const int* in_sizes, int n_in,
                              void* d_out, int out_size, void* d_ws, size_t ws_size,
                              hipStream_t stream) {
    const float* t    = (const float*)d_in[0];
    const float* z    = (const float*)d_in[1];
    const float* cond = (const float*)d_in[2];
    const float* W0   = (const float*)d_in[3];
    const float* b0   = (const float*)d_in[4];
    const float* g0   = (const float*)d_in[5];
    const float* be0  = (const float*)d_in[6];
    const float* W1   = (const float*)d_in[7];
    const float* b1   = (const float*)d_in[8];
    const float* g1   = (const float*)d_in[9];
    const float* be1  = (const float*)d_in[10];
    const float* W2   = (const float*)d_in[11];
    const float* b2   = (const float*)d_in[12];
    const float* g2   = (const float*)d_in[13];
    const float* be2  = (const float*)d_in[14];
    const float* W3   = (const float*)d_in[15];
    const float* b3   = (const float*)d_in[16];
    float* out = (float*)d_out;

    ushort_t* Wt0 = (ushort_t*)d_ws;                    // 512*160
    ushort_t* Wt1 = Wt0 + 512 * K0P;                    // 512*544
    ushort_t* Wt2 = Wt1 + 512 * KHP;                    // 512*544

    hipLaunchKernelGGL(prep_w, dim3(512), dim3(256), 0, stream, W0, Wt0, 132, K0P);
    hipLaunchKernelGGL(prep_w, dim3(512), dim3(256), 0, stream, W1, Wt1, 514, KHP);
    hipLaunchKernelGGL(prep_w, dim3(512), dim3(256), 0, stream, W2, Wt2, 514, KHP);

    hipLaunchKernelGGL(ode_mfma, dim3(NTOK / TM), dim3(256), 0, stream,
                       t, z, cond, Wt0, Wt1, Wt2,
                       b0, g0, be0, b1, g1, be1, b2, g2, be2, W3, b3, out);
}

// Round 3
// 1027.855 us; speedup vs baseline: 15.9279x; 1.4060x over previous
//
#include <hip/hip_runtime.h>
#include <math.h>

typedef unsigned short ushort_t;
typedef unsigned int uint_t;
typedef __attribute__((ext_vector_type(8))) short bf16x8;
typedef __attribute__((ext_vector_type(4))) float f32x4;

#define NTOK 131072          // B*S
#define TM 16                // tokens per block
#define SROW 584             // A row stride in bf16 elems (292 dw, 292%32==4 -> conflict-free)
#define K0P 160              // layer0 K padded (132 -> 160)
#define KHP 544              // hidden layers K padded (514 -> 544)
#define EPS 1e-5f

__device__ __forceinline__ ushort_t f2bf(float f) {
    uint_t x = __float_as_uint(f);
    x += 0x7FFFu + ((x >> 16) & 1u);   // RNE
    return (ushort_t)(x >> 16);
}
__device__ __forceinline__ float bf2f(ushort_t u) {
    return __uint_as_float(((uint_t)u) << 16);
}

// ---- weight prep: W[K][512] fp32 -> Wt[n][k] bf16, zero-padded to Kpad ----
__global__ __launch_bounds__(256) void prep_w(const float* __restrict__ W,
                                              ushort_t* __restrict__ dst,
                                              int K, int Kpad) {
    int n = blockIdx.x;            // 0..511
    for (int k = threadIdx.x; k < Kpad; k += 256) {
        float v = (k < K) ? W[k * 512 + n] : 0.0f;
        dst[n * Kpad + k] = f2bf(v);
    }
}

// One fused layer: 48x512 GEMM (primal + 2 tangents share B), bias, LN+softplus
// primal + LN/softplus JVP on tangents, bf16 write-back to A.
template<int KPAD>
__device__ __forceinline__ void do_layer(
    const ushort_t* __restrict__ Wt, const float* __restrict__ bb,
    const float* __restrict__ gg, const float* __restrict__ bev,
    ushort_t* A_s, float (*sbuf)[16][6], float (*pbuf)[8])
{
    const int tid  = threadIdx.x;
    const int w    = tid >> 6;      // wave 0..7
    const int lane = tid & 63;
    const int q    = lane >> 4;     // quad 0..3
    const int c16  = lane & 15;
    const int nb   = w * 64;        // wave's 64-column base

    f32x4 acc[3][4];
#pragma unroll
    for (int m = 0; m < 3; m++)
#pragma unroll
        for (int j = 0; j < 4; j++) acc[m][j] = (f32x4){0.f, 0.f, 0.f, 0.f};

    const int koff = q * 8;
    const ushort_t* bp = Wt + (nb + c16) * KPAD + koff;
    const ushort_t* ap = A_s + c16 * SROW + koff;

    for (int ks = 0; ks < KPAD / 32; ks++) {
        bf16x8 af[3], bf[4];
#pragma unroll
        for (int m = 0; m < 3; m++)
            af[m] = *(const bf16x8*)(ap + m * 16 * SROW + ks * 32);
#pragma unroll
        for (int j = 0; j < 4; j++)
            bf[j] = *(const bf16x8*)(bp + j * 16 * KPAD + ks * 32);
#pragma unroll
        for (int m = 0; m < 3; m++)
#pragma unroll
            for (int j = 0; j < 4; j++)
                acc[m][j] = __builtin_amdgcn_mfma_f32_16x16x32_bf16(af[m], bf[j], acc[m][j], 0, 0, 0);
    }

    // bias on primal rows
#pragma unroll
    for (int j = 0; j < 4; j++) {
        float bv = bb[nb + 16 * j + c16];
#pragma unroll
        for (int r = 0; r < 4; r++) acc[0][j][r] += bv;
    }

    // wave-local LN stats (6 sums per token over this wave's 64 cols)
    float st[4][6];
#pragma unroll
    for (int r = 0; r < 4; r++) {
        float s1 = 0.f, s2 = 0.f, a0 = 0.f, x0 = 0.f, a1 = 0.f, x1 = 0.f;
#pragma unroll
        for (int j = 0; j < 4; j++) {
            float p = acc[0][j][r], u0 = acc[1][j][r], u1 = acc[2][j][r];
            s1 += p; s2 += p * p;
            a0 += u0; x0 += p * u0;
            a1 += u1; x1 += p * u1;
        }
        st[r][0] = s1; st[r][1] = s2; st[r][2] = a0; st[r][3] = x0; st[r][4] = a1; st[r][5] = x1;
    }
#pragma unroll
    for (int d = 1; d <= 8; d <<= 1)
#pragma unroll
        for (int r = 0; r < 4; r++)
#pragma unroll
            for (int s = 0; s < 6; s++) st[r][s] += __shfl_xor(st[r][s], d);
    if (c16 == 0) {
#pragma unroll
        for (int r = 0; r < 4; r++)
#pragma unroll
            for (int s = 0; s < 6; s++) sbuf[w][4 * q + r][s] = st[r][s];
    }
    __syncthreads();

    // one thread per token finalizes LN params
    if (tid < TM) {
        float s[6] = {0.f, 0.f, 0.f, 0.f, 0.f, 0.f};
#pragma unroll
        for (int ww = 0; ww < 8; ww++)
#pragma unroll
            for (int k = 0; k < 6; k++) s[k] += sbuf[ww][tid][k];
        const float inv = 1.0f / 512.0f;
        float mu  = s[0] * inv;
        float var = s[1] * inv - mu * mu;
        float rs  = rsqrtf(var + EPS);
        float dm0 = s[2] * inv, dm1 = s[4] * inv;
        float c0 = rs * (s[3] * inv - mu * dm0);
        float c1 = rs * (s[5] * inv - mu * dm1);
        pbuf[tid][0] = mu; pbuf[tid][1] = rs;
        pbuf[tid][2] = dm0; pbuf[tid][3] = c0;
        pbuf[tid][4] = dm1; pbuf[tid][5] = c1;
    }
    __syncthreads();

    // epilogue: softplus(LN) + JVP, bf16 write-back
    float gv[4], bvv[4];
#pragma unroll
    for (int j = 0; j < 4; j++) {
        gv[j]  = gg[nb + 16 * j + c16];
        bvv[j] = bev[nb + 16 * j + c16];
    }
#pragma unroll
    for (int r = 0; r < 4; r++) {
        int tok = 4 * q + r;
        float4 pa = *(const float4*)&pbuf[tok][0];
        float4 pb = *(const float4*)&pbuf[tok][4];
        float mu = pa.x, rs = pa.y, dm0 = pa.z, c0 = pa.w;
        float dm1 = pb.x, c1 = pb.y;
#pragma unroll
        for (int j = 0; j < 4; j++) {
            int n = nb + 16 * j + c16;
            float p  = acc[0][j][r], u0 = acc[1][j][r], u1 = acc[2][j][r];
            float xh = (p - mu) * rs;
            float y  = fmaf(xh, gv[j], bvv[j]);
            float e  = __expf(-fabsf(y));
            float rinv = 1.0f / (1.0f + e);
            float sig  = (y >= 0.f) ? rinv : e * rinv;
            float sp   = fmaxf(y, 0.f) + __logf(1.0f + e);
            float grs  = gv[j] * rs;
            float dy0  = grs * (u0 - dm0 - xh * c0);
            float dy1  = grs * (u1 - dm1 - xh * c1);
            A_s[tok * SROW + 2 + n]        = f2bf(sp);
            A_s[(16 + tok) * SROW + 2 + n] = f2bf(sig * dy0);
            A_s[(32 + tok) * SROW + 2 + n] = f2bf(sig * dy1);
        }
    }
    __syncthreads();
}

__global__ __launch_bounds__(512, 4) void ode_mfma(
    const float* __restrict__ t, const float* __restrict__ z, const float* __restrict__ cond,
    const ushort_t* __restrict__ Wt0, const ushort_t* __restrict__ Wt1, const ushort_t* __restrict__ Wt2,
    const float* __restrict__ b0, const float* __restrict__ g0, const float* __restrict__ be0,
    const float* __restrict__ b1, const float* __restrict__ g1, const float* __restrict__ be1,
    const float* __restrict__ b2, const float* __restrict__ g2, const float* __restrict__ be2,
    const float* __restrict__ W3, const float* __restrict__ b3,
    float* __restrict__ out)
{
    __shared__ ushort_t A_s[48 * SROW];       // rows 0..15 primal x, 16..31 u0, 32..47 u1
    __shared__ float sbuf[8][16][6];
    __shared__ float pbuf[16][8];

    const int tid = threadIdx.x;

    // ---------------- init A ----------------
    {   uint_t* A32 = (uint_t*)A_s;
        for (int i = tid; i < 48 * SROW / 2; i += 512) A32[i] = 0u;
    }
    __syncthreads();
    const float te = t[0];
    if (tid < TM) {
        int tok = tid;
        int gm  = blockIdx.x * TM + tok;
        int si  = gm & 63;
        float pos = (float)(si + 1) * (1.0f / 64.0f);
        A_s[tok * SROW + 0] = f2bf(te);
        A_s[tok * SROW + 1] = f2bf(pos);
        A_s[tok * SROW + 2] = f2bf(z[gm * 2 + 0]);
        A_s[tok * SROW + 3] = f2bf(z[gm * 2 + 1]);
        A_s[(16 + tok) * SROW + 2] = 0x3F80;   // u0 = e0 (bf16 1.0)
        A_s[(32 + tok) * SROW + 3] = 0x3F80;   // u1 = e1
    }
    {   // all 16 tokens of a block share one batch row (16 | 64)
        int bi = (blockIdx.x * TM) >> 6;
        for (int i = tid; i < TM * 128; i += 512) {
            int tok = i >> 7, c = i & 127;
            A_s[tok * SROW + 4 + c] = f2bf(cond[bi * 128 + c]);
        }
    }
    __syncthreads();

    do_layer<K0P>(Wt0, b0, g0, be0, A_s, sbuf, pbuf);
    do_layer<KHP>(Wt1, b1, g1, be1, A_s, sbuf, pbuf);
    do_layer<KHP>(Wt2, b2, g2, be2, A_s, sbuf, pbuf);

    // ---------------- layer 3: Kin=514 -> 2 outputs + divergence ----------------
    {
        int tok = tid >> 5;       // 0..15
        int l32 = tid & 31;
        int gm  = blockIdx.x * TM + tok;
        const float2* W3v = (const float2*)W3;
        float a0 = 0.f, a1 = 0.f, d0 = 0.f, d1 = 0.f;
        for (int k = l32; k < 514; k += 32) {
            float2 wv = W3v[k];
            float ax  = bf2f(A_s[tok * SROW + k]);
            float au0 = bf2f(A_s[(16 + tok) * SROW + k]);
            float au1 = bf2f(A_s[(32 + tok) * SROW + k]);
            a0 = fmaf(ax, wv.x, a0);
            a1 = fmaf(ax, wv.y, a1);
            d0 = fmaf(au0, wv.x, d0);
            d1 = fmaf(au1, wv.y, d1);
        }
#pragma unroll
        for (int d = 1; d <= 16; d <<= 1) {
            a0 += __shfl_xor(a0, d); a1 += __shfl_xor(a1, d);
            d0 += __shfl_xor(d0, d); d1 += __shfl_xor(d1, d);
        }
        if (l32 == 0) {
            out[gm * 2 + 0]    = a0 + b3[0];
            out[gm * 2 + 1]    = a1 + b3[1];
            out[NTOK * 2 + gm] = -(d0 + d1);
        }
    }
}

extern "C" void kernel_launch(void* const* d_in, const int* in_sizes, int n_in,
                              void* d_out, int out_size, void* d_ws, size_t ws_size,
                              hipStream_t stream) {
    const float* t    = (const float*)d_in[0];
    const float* z    = (const float*)d_in[1];
    const float* cond = (const float*)d_in[2];
    const float* W0   = (const float*)d_in[3];
    const float* b0   = (const float*)d_in[4];
    const float* g0   = (const float*)d_in[5];
    const float* be0  = (const float*)d_in[6];
    const float* W1   = (const float*)d_in[7];
    const float* b1   = (const float*)d_in[8];
    const float* g1   = (const float*)d_in[9];
    const float* be1  = (const float*)d_in[10];
    const float* W2   = (const float*)d_in[11];
    const float* b2   = (const float*)d_in[12];
    const float* g2   = (const float*)d_in[13];
    const float* be2  = (const float*)d_in[14];
    const float* W3   = (const float*)d_in[15];
    const float* b3   = (const float*)d_in[16];
    float* out = (float*)d_out;

    ushort_t* Wt0 = (ushort_t*)d_ws;                    // 512*160
    ushort_t* Wt1 = Wt0 + 512 * K0P;                    // 512*544
    ushort_t* Wt2 = Wt1 + 512 * KHP;                    // 512*544

    hipLaunchKernelGGL(prep_w, dim3(512), dim3(256), 0, stream, W0, Wt0, 132, K0P);
    hipLaunchKernelGGL(prep_w, dim3(512), dim3(256), 0, stream, W1, Wt1, 514, KHP);
    hipLaunchKernelGGL(prep_w, dim3(512), dim3(256), 0, stream, W2, Wt2, 514, KHP);

    hipLaunchKernelGGL(ode_mfma, dim3(NTOK / TM), dim3(512), 0, stream,
                       t, z, cond, Wt0, Wt1, Wt2,
                       b0, g0, be0, b1, g1, be1, b2, g2, be2, W3, b3, out);
}